// Round 16
// baseline (363.173 us; speedup 1.0000x reference)
//
#include <hip/hip_runtime.h>
#include <hip/hip_bf16.h>

using short4v = __attribute__((ext_vector_type(4))) short;
using short8 = __attribute__((ext_vector_type(8))) short;
using f32x4  = __attribute__((ext_vector_type(4))) float;

#define SEQ 2048
#define NHEAD 32
#define NKVH 4
#define HDIM 128
// 1/sqrt(128) * log2(e)  -- exp2-domain softmax, folded into Q at pack time
#define QK_SCALE_LOG2 (0.08838834764831845f * 1.44269504088896340f)

__device__ __forceinline__ float fast_exp2(float x) { return __builtin_amdgcn_exp2f(x); }
__device__ __forceinline__ float b2f(short u) {
    return __uint_as_float(((unsigned)(unsigned short)u) << 16);
}
__device__ __forceinline__ short f2bb(float f) {
    __hip_bfloat16 h = __float2bfloat16(f);
    return *reinterpret_cast<short*>(&h);
}
__device__ __forceinline__ void gload_lds16(const __hip_bfloat16* src, __hip_bfloat16* dst) {
    __builtin_amdgcn_global_load_lds((const __attribute__((address_space(1))) void*)src,
                                     (__attribute__((address_space(3))) void*)dst, 16, 0, 0);
}

// ---------------------------------------------------------------- fused prep: cast hs + transpose wq/wk/wv/wo
__global__ __launch_bounds__(256) void prep_kernel(
    const float* __restrict__ hs, __hip_bfloat16* __restrict__ hsb,
    const float* __restrict__ wq, const float* __restrict__ wk, const float* __restrict__ wv,
    const float* __restrict__ wo,
    __hip_bfloat16* __restrict__ WqkvT, __hip_bfloat16* __restrict__ WoT) {
    const int b = blockIdx.x, tid = threadIdx.x;
    if (b < 4096) {
        int i = b * 256 + tid;
        float4 v = ((const float4*)hs)[i];
        __hip_bfloat16 h4[4] = {__float2bfloat16(v.x), __float2bfloat16(v.y),
                                __float2bfloat16(v.z), __float2bfloat16(v.w)};
        ((ushort4*)hsb)[i] = *(ushort4*)h4;
        return;
    }
    __shared__ float tile[32][33];
    const float* W; __hip_bfloat16* Wt; int N, ld, nb, kb;
    if (b < 12288)      { int bb = b - 4096;  W = wq; Wt = WqkvT;                       N = 4096; ld = 2048; nb = (bb & 127) * 32; kb = (bb >> 7) * 32; }
    else if (b < 13312) { int bb = b - 12288; W = wk; Wt = WqkvT + (size_t)4096 * 2048; N = 512;  ld = 2048; nb = (bb & 15) * 32;  kb = (bb >> 4) * 32; }
    else if (b < 14336) { int bb = b - 13312; W = wv; Wt = WqkvT + (size_t)4608 * 2048; N = 512;  ld = 2048; nb = (bb & 15) * 32;  kb = (bb >> 4) * 32; }
    else                { int bb = b - 14336; W = wo; Wt = WoT;                         N = 2048; ld = 4096; nb = (bb & 63) * 32;  kb = (bb >> 6) * 32; }
    int tx = tid & 31, ty = tid >> 5;   // 32 x 8
    for (int j = 0; j < 32; j += 8)
        tile[ty + j][tx] = W[(size_t)(kb + ty + j) * N + nb + tx];
    __syncthreads();
    for (int j = 0; j < 32; j += 8)
        Wt[(size_t)(nb + ty + j) * ld + kb + tx] = __float2bfloat16(tile[tx][ty + j]);
}

// ---------------------------------------------------------------- GEMM: A(M,*)bf16 x Bt(N,*)bf16 -> C(M,N)
// BK=64, XOR-swizzled LDS (R12 structure: coalesced staging + swizzled reads).
// RED3: split-K=3 fused deterministic reduction -- every z-block writes its
// bf16 partial, fences, bumps a per-tile counter; the LAST block re-reads all
// three partials in fixed order p0+p1+p2 (order-independent value) and writes
// the fp32 final. cnt must be zeroed before launch (hipMemsetAsync).
#define BM 128
#define BN 128
#define BK2 64
template <typename OutT, bool RED3>
__global__ __launch_bounds__(256) void gemm_bt_kernel(
    const __hip_bfloat16* __restrict__ A, const __hip_bfloat16* __restrict__ Bt,
    OutT* __restrict__ C, int M, int N, int KextMax, int ld, int koff, long long czstride, int Ktot,
    float* __restrict__ fout, int* __restrict__ cnt) {
    const int kstart = blockIdx.z * koff;
    const int Kext = min(KextMax, Ktot - kstart);
    OutT* Cbase = C;
    A  += (size_t)kstart;
    Bt += (size_t)kstart;
    C  += (size_t)blockIdx.z * czstride;
    __shared__ __align__(16) __hip_bfloat16 sA[BM * BK2];   // 16 KB
    __shared__ __align__(16) __hip_bfloat16 sB[BN * BK2];   // 16 KB
    const int tid = threadIdx.x;
    const int w = tid >> 6, l = tid & 63;
    const int wr = w >> 1, wc = w & 1;
    const int row0 = blockIdx.y * BM;
    const int col0 = blockIdx.x * BN;
    const int fr = l & 15;
    const int fq = l >> 4;
    const int xs = (fr & 7) << 4;       // read-side XOR (bytes)

    f32x4 acc[4][4] = {};

    for (int k0 = 0; k0 < Kext; k0 += BK2) {
        for (int i = 0; i < 4; ++i) {
            int ch = i * 256 + tid;                 // 0..1023
            int row = ch >> 3;                      // 0..127
            int cb = ((ch & 7) * 16) ^ ((row & 7) << 4);   // pre-swizzled source col (bytes)
            gload_lds16(A  + (size_t)(row0 + row) * ld + k0 + (cb >> 1), &sA[ch * 8]);
            gload_lds16(Bt + (size_t)(col0 + row) * ld + k0 + (cb >> 1), &sB[ch * 8]);
        }
        __syncthreads();
        short8 af[4][2], bfr[4][2];
        for (int m = 0; m < 4; ++m) {
            const char* base = (const char*)sA + (wr * 64 + m * 16 + fr) * 128;
            af[m][0] = *(const short8*)(base + (((fq) * 16)     ^ xs));
            af[m][1] = *(const short8*)(base + (((fq + 4) * 16) ^ xs));
        }
        for (int n = 0; n < 4; ++n) {
            const char* base = (const char*)sB + (wc * 64 + n * 16 + fr) * 128;
            bfr[n][0] = *(const short8*)(base + (((fq) * 16)     ^ xs));
            bfr[n][1] = *(const short8*)(base + (((fq + 4) * 16) ^ xs));
        }
        for (int kk = 0; kk < 2; ++kk)
            for (int m = 0; m < 4; ++m)
                for (int n = 0; n < 4; ++n)
                    acc[m][n] = __builtin_amdgcn_mfma_f32_16x16x32_bf16(af[m][kk], bfr[n][kk], acc[m][n], 0, 0, 0);
        __syncthreads();
    }
    for (int m = 0; m < 4; ++m)
        for (int n = 0; n < 4; ++n)
            for (int r = 0; r < 4; ++r) {
                int row = row0 + wr * 64 + m * 16 + fq * 4 + r;
                int col = col0 + wc * 64 + n * 16 + fr;
                float v = acc[m][n][r];
                if constexpr (__is_same(OutT, float)) C[(size_t)row * N + col] = v;
                else C[(size_t)row * N + col] = __float2bfloat16(v);
            }
    if constexpr (RED3) {
        __shared__ int lastf;
        __threadfence();                 // make this block's partial visible device-wide
        __syncthreads();
        if (tid == 0)
            lastf = (atomicAdd(&cnt[blockIdx.y * gridDim.x + blockIdx.x], 1) == (int)gridDim.z - 1);
        __syncthreads();
        if (lastf) {
            __threadfence();             // acquire: other partials now visible
            const short* pb = (const short*)Cbase;
            for (int m = 0; m < 4; ++m)
                for (int n = 0; n < 4; ++n)
                    for (int r = 0; r < 4; ++r) {
                        int row = row0 + wr * 64 + m * 16 + fq * 4 + r;
                        int col = col0 + wc * 64 + n * 16 + fr;
                        size_t idx = (size_t)row * N + col;
                        float v = b2f(pb[idx]) + b2f(pb[idx + czstride]) + b2f(pb[idx + 2 * czstride]);
                        fout[idx] = v;
                    }
        }
    }
}

// ---------------------------------------------------------------- fused partial-add + RMSNorm + RoPE + pack (vectorized)
__global__ __launch_bounds__(256) void pack_kernel(
    const __hip_bfloat16* __restrict__ P0, const __hip_bfloat16* __restrict__ P1,
    const float* __restrict__ cosp, const float* __restrict__ sinp,
    const float* __restrict__ qnw, const float* __restrict__ knw,
    __hip_bfloat16* __restrict__ Qh, __hip_bfloat16* __restrict__ Kh, __hip_bfloat16* __restrict__ Vt) {
    const int tid = threadIdx.x;
    const int rloc = tid >> 4, l16 = tid & 15;
    const int r = blockIdx.y * 16 + rloc;          // 0..79
    const int s = blockIdx.x * 2 + (r >= 40 ? 1 : 0);
    const int slot = (r >= 40) ? r - 40 : r;
    int off;
    if (slot < 32)      off = slot * 128;
    else if (slot < 36) off = 4096 + (slot - 32) * 128;
    else                off = 4608 + (slot - 36) * 128;
    const int d0 = l16 * 4;
    const size_t base = (size_t)s * 5120 + off;

    short4v a0 = *(const short4v*)&P0[base + d0];
    short4v a1 = *(const short4v*)&P0[base + d0 + 64];
    short4v b0 = *(const short4v*)&P1[base + d0];
    short4v b1 = *(const short4v*)&P1[base + d0 + 64];
    float x1[4], x2[4];
    for (int j = 0; j < 4; ++j) {
        x1[j] = b2f(a0[j]) + b2f(b0[j]);
        x2[j] = b2f(a1[j]) + b2f(b1[j]);
    }

    if (slot >= 36) {   // V: cast + transpose to (D,S)
        int t = slot - 36;
        for (int j = 0; j < 4; ++j) {
            Vt[((size_t)t * 128 + d0 + j) * SEQ + s]      = __float2bfloat16(x1[j]);
            Vt[((size_t)t * 128 + d0 + 64 + j) * SEQ + s] = __float2bfloat16(x2[j]);
        }
        return;
    }
    float ss = 0.f;
    for (int j = 0; j < 4; ++j) ss += x1[j] * x1[j] + x2[j] * x2[j];
    for (int x = 1; x < 16; x <<= 1) ss += __shfl_xor(ss, x);
    float rs = rsqrtf(ss * (1.0f / 128.0f) + 1e-6f);

    f32x4 c4 = *(const f32x4*)&cosp[(size_t)s * 128 + d0];   // cos[d]==cos[d+64]
    f32x4 s4 = *(const f32x4*)&sinp[(size_t)s * 128 + d0];
    const float* wgt = (slot < 32) ? qnw : knw;
    f32x4 w1 = *(const f32x4*)&wgt[d0];
    f32x4 w2 = *(const f32x4*)&wgt[d0 + 64];
    const float scl = (slot < 32) ? QK_SCALE_LOG2 : 1.0f;

    short4v o1, o2;
    for (int j = 0; j < 4; ++j) {
        float a = x1[j] * rs * w1[j], b = x2[j] * rs * w2[j];
        o1[j] = f2bb((a * c4[j] - b * s4[j]) * scl);
        o2[j] = f2bb((b * c4[j] + a * s4[j]) * scl);
    }
    __hip_bfloat16* dst;
    if (slot < 32) dst = Qh + ((size_t)slot * SEQ + s) * 128;
    else           dst = Kh + ((size_t)(slot - 32) * SEQ + s) * 128;
    *(short4v*)&dst[d0]      = o1;
    *(short4v*)&dst[d0 + 64] = o2;
}

// ---------------------------------------------------------------- causal GQA flash attention
// Swapped QK^T (R10/R12) + complementary q-tile pairing (R14): each wave
// handles q-tiles qtA = bx>>3 and 127-qtA in one k-loop; 512 uniform blocks.
__global__ __launch_bounds__(256, 2) void attn_kernel(
    const __hip_bfloat16* __restrict__ Qh,  // [NH][S][D], scale*log2e folded
    const __hip_bfloat16* __restrict__ Kh,  // [NKV][S][D]
    const __hip_bfloat16* __restrict__ Vt,  // [NKV][D][S]
    __hip_bfloat16* __restrict__ Oa) {      // [S][NH*D]
    __shared__ __align__(16) __hip_bfloat16 sK[2][64 * 128];   // 2 x 16 KB
    __shared__ __align__(16) __hip_bfloat16 sV[2][128 * 64];   // 2 x 16 KB
    __shared__ __align__(16) __hip_bfloat16 sP[4][16 * 72];    // per-wave P (reused A,B)

    const int tid = threadIdx.x;
    const int w = tid >> 6, l = tid & 63;
    const int bx = blockIdx.x;
    const int y = bx & 7;                      // kv-slice
    const int qtA = bx >> 3;                   // 0..63
    const int qbaseA = qtA * 16;
    const int qbaseB = (127 - qtA) * 16;
    const int hkv = y >> 1;
    const int h = y * 4 + w;                   // this wave's q-head
    const int fr = l & 15, g = l >> 4;

    const __hip_bfloat16* Kp = Kh + (size_t)hkv * SEQ * HDIM;
    const __hip_bfloat16* Vp = Vt + (size_t)hkv * HDIM * SEQ;
    char* myP = (char*)&sP[w][0];

    short8 qfA[4], qfB[4];
    {
        const __hip_bfloat16* QpA = Qh + ((size_t)h * SEQ + qbaseA) * HDIM;
        const __hip_bfloat16* QpB = Qh + ((size_t)h * SEQ + qbaseB) * HDIM;
        for (int c = 0; c < 4; ++c) {
            qfA[c] = *(const short8*)&QpA[fr * HDIM + c * 32 + g * 8];
            qfB[c] = *(const short8*)&QpB[fr * HDIM + c * 32 + g * 8];
        }
    }

    f32x4 oaccA[8] = {}, oaccB[8] = {};
    float msA = -3.0e38f, lsA = 0.f;
    float msB = -3.0e38f, lsB = 0.f;

    const int xr = (fr & 7) << 4;              // XOR-swizzle byte offset (read side)
    const int qgA = qbaseA + fr;
    const int qgB = qbaseB + fr;
    const int nA = ((qbaseA + 15) >> 6) + 1;
    const int nB = ((qbaseB + 15) >> 6) + 1;   // nB >= nA

    auto stage = [&](int buf, int kbase) {
        for (int i = 0; i < 4; ++i) {
            int blk = i * 4 + w;               // 0..15, uniform per wave
            {   // K
                int row = blk * 4 + (l >> 4);
                int cb = ((l & 15) * 16) ^ ((row & 7) << 4);
                gload_lds16(Kp + (size_t)(kbase + row) * HDIM + (cb >> 1), &sK[buf][blk * 512]);
            }
            {   // V
                int row = blk * 8 + (l >> 3);
                int cb = ((l & 7) * 16) ^ ((row & 7) << 4);
                gload_lds16(Vp + (size_t)row * SEQ + kbase + (cb >> 1), &sV[buf][blk * 512]);
            }
        }
    };

    // one q-tile's per-k-tile work (swapped QK^T softmax); all indices static
#define PROCESS(QF, OACC, MS, LS, QG, QBASE)                                           \
    {                                                                                  \
        f32x4 s[4] = {};                                                               \
        __builtin_amdgcn_s_setprio(1);                                                 \
        for (int j = 0; j < 4; ++j) {                                                  \
            const __hip_bfloat16* kp = &sK[buf][(j * 16 + fr) * 128];                  \
            for (int c = 0; c < 4; ++c) {                                              \
                short8 kf = *(const short8*)&kp[((c * 64 + g * 16) ^ xr) >> 1];        \
                s[j] = __builtin_amdgcn_mfma_f32_16x16x32_bf16(kf, QF[c], s[j], 0, 0, 0); \
            }                                                                          \
        }                                                                              \
        __builtin_amdgcn_s_setprio(0);                                                 \
        float v[4][4];                                                                 \
        const bool full = (kbase + 63 <= (QBASE));                                     \
        if (full) {                                                                    \
            for (int j = 0; j < 4; ++j)                                                \
                for (int r = 0; r < 4; ++r) v[j][r] = s[j][r];                         \
        } else {                                                                       \
            const int kb0 = kbase + g * 4;                                             \
            for (int j = 0; j < 4; ++j)                                                \
                for (int r = 0; r < 4; ++r)                                            \
                    v[j][r] = (kb0 + j * 16 + r <= (QG)) ? s[j][r] : -1e30f;           \
        }                                                                              \
        float m0 = fmaxf(fmaxf(v[0][0], v[0][1]), fmaxf(v[0][2], v[0][3]));            \
        float m1 = fmaxf(fmaxf(v[1][0], v[1][1]), fmaxf(v[1][2], v[1][3]));            \
        float m2 = fmaxf(fmaxf(v[2][0], v[2][1]), fmaxf(v[2][2], v[2][3]));            \
        float m3 = fmaxf(fmaxf(v[3][0], v[3][1]), fmaxf(v[3][2], v[3][3]));            \
        float m = fmaxf(fmaxf(m0, m1), fmaxf(m2, m3));                                 \
        m = fmaxf(m, __shfl_xor(m, 16));                                               \
        m = fmaxf(m, __shfl_xor(m, 32));                                               \
        if (__any(m > MS + 12.0f)) {                                                   \
            float mnew = fmaxf(MS, m);                                                 \
            float corr = fast_exp2(MS - mnew);                                         \
            MS = mnew;                                                                 \
            LS *= corr;                                                                \
            float c0 = __shfl(corr, g * 4 + 0);                                        \
            float c1 = __shfl(corr, g * 4 + 1);                                        \
            float c2 = __shfl(corr, g * 4 + 2);                                        \
            float c3 = __shfl(corr, g * 4 + 3);                                        \
            for (int dt = 0; dt < 8; ++dt) {                                           \
                OACC[dt][0] *= c0; OACC[dt][1] *= c1;                                  \
                OACC[dt][2] *= c2; OACC[dt][3] *= c3;                                  \
            }                                                                          \
        }                                                                              \
        for (int j = 0; j < 4; ++j) {                                                  \
            float e0 = fast_exp2(v[j][0] - MS);                                        \
            float e1 = fast_exp2(v[j][1] - MS);                                        \
            float e2 = fast_exp2(v[j][2] - MS);                                        \
            float e3 = fast_exp2(v[j][3] - MS);                                        \
            LS += (e0 + e1) + (e2 + e3);                                               \
            short4v pw = {f2bb(e0), f2bb(e1), f2bb(e2), f2bb(e3)};                     \
            *(short4v*)(myP + fr * 144 + j * 32 + g * 8) = pw;                         \
        }                                                                              \
        short8 pa0 = *(const short8*)(myP + fr * 144 + g * 16);                        \
        short8 pa1 = *(const short8*)(myP + fr * 144 + 64 + g * 16);                   \
        __builtin_amdgcn_s_setprio(1);                                                 \
        for (int dt = 0; dt < 8; ++dt) {                                               \
            const __hip_bfloat16* vp = &sV[buf][(dt * 16 + fr) * 64];                  \
            short8 vb0 = *(const short8*)&vp[((g * 16)      ^ xr) >> 1];               \
            short8 vb1 = *(const short8*)&vp[((g * 16 + 64) ^ xr) >> 1];               \
            OACC[dt] = __builtin_amdgcn_mfma_f32_16x16x32_bf16(pa0, vb0, OACC[dt], 0, 0, 0); \
            OACC[dt] = __builtin_amdgcn_mfma_f32_16x16x32_bf16(pa1, vb1, OACC[dt], 0, 0, 0); \
        }                                                                              \
        __builtin_amdgcn_s_setprio(0);                                                 \
    }

    stage(0, 0);
    __syncthreads();                            // drains vmcnt(0): tile 0 ready

    for (int t = 0; t < nB; ++t) {
        const int kbase = t * 64;
        const int buf = t & 1;
        if (t + 1 < nB) stage(buf ^ 1, kbase + 64);   // overlap with compute

        if (t < nA) PROCESS(qfA, oaccA, msA, lsA, qgA, qbaseA);
        PROCESS(qfB, oaccB, msB, lsB, qgB, qbaseB);

        __syncthreads();   // next tile staged (vmcnt 0) + all waves done with buf[t]
    }
#undef PROCESS

    // ---- finalize both q-tiles
    lsA += __shfl_xor(lsA, 16); lsA += __shfl_xor(lsA, 32);
    lsB += __shfl_xor(lsB, 16); lsB += __shfl_xor(lsB, 32);
    float invA[4], invB[4];
    for (int r = 0; r < 4; ++r) {
        invA[r] = 1.0f / __shfl(lsA, g * 4 + r);
        invB[r] = 1.0f / __shfl(lsB, g * 4 + r);
    }
    for (int dt = 0; dt < 8; ++dt)
        for (int r = 0; r < 4; ++r) {
            int qA = qbaseA + g * 4 + r;
            int qB = qbaseB + g * 4 + r;
            Oa[(size_t)qA * (NHEAD * HDIM) + h * HDIM + dt * 16 + fr] =
                __float2bfloat16(oaccA[dt][r] * invA[r]);
            Oa[(size_t)qB * (NHEAD * HDIM) + h * HDIM + dt * 16 + fr] =
                __float2bfloat16(oaccB[dt][r] * invB[r]);
        }
}

// ---------------------------------------------------------------- launch
extern "C" void kernel_launch(void* const* d_in, const int* in_sizes, int n_in,
                              void* d_out, int out_size, void* d_ws, size_t ws_size,
                              hipStream_t stream) {
    const float* hs   = (const float*)d_in[0];
    const float* cosp = (const float*)d_in[1];
    const float* sinp = (const float*)d_in[2];
    const float* wq   = (const float*)d_in[3];
    const float* wk   = (const float*)d_in[4];
    const float* wv   = (const float*)d_in[5];
    const float* wo   = (const float*)d_in[6];
    const float* qnw  = (const float*)d_in[7];
    const float* knw  = (const float*)d_in[8];
    float* out = (float*)d_out;
    char* ws = (char*)d_ws;

    // workspace timeline (88,080,384 B):
    // phase1 prep:  hsb[0,8.39M) WqkvT[8.39M,29.36M) WoT[29.36M,46.14M)
    // phase2 gemm1: P0[46.14M,67.11M) P1[67.11M,88.08M)  (bf16, split-K=2)
    // phase3 pack:  Qh[8.39M,25.17M) Kh[25.17M,27.26M) Vt[27.26M,29.36M)  (over dead WqkvT)
    // phase4 attn:  Oa[46.14M,62.91M)                                     (over dead P0)
    // phase5 gemm2: Qb[0,25.17M) split-K=3 partials; cnt[27.26M,+1K)      (over dead hsb/Qh/Kh/Vt)
    __hip_bfloat16* hsb    = (__hip_bfloat16*)(ws);
    __hip_bfloat16* WqkvT  = (__hip_bfloat16*)(ws + 8388608);
    __hip_bfloat16* WoT    = (__hip_bfloat16*)(ws + 29360128);
    __hip_bfloat16* P0     = (__hip_bfloat16*)(ws + 46137344);
    __hip_bfloat16* P1     = (__hip_bfloat16*)(ws + 67108864);
    __hip_bfloat16* Qh     = (__hip_bfloat16*)(ws + 8388608);
    __hip_bfloat16* Kh     = (__hip_bfloat16*)(ws + 25165824);
    __hip_bfloat16* Vt     = (__hip_bfloat16*)(ws + 27262976);
    __hip_bfloat16* Oa     = (__hip_bfloat16*)(ws + 46137344);
    __hip_bfloat16* Qb     = (__hip_bfloat16*)(ws);              // 3 x 8,388,608 B
    int*            cnt    = (int*)(ws + 27262976);              // 256 tile counters

    prep_kernel<<<22528, 256, 0, stream>>>(hs, hsb, wq, wk, wv, wo, WqkvT, WoT);
    // QKV projection, split-K=2 (K=1024 each, 16 BK64-steps), bf16 partials
    gemm_bt_kernel<__hip_bfloat16, false><<<dim3(40, 16, 2), 256, 0, stream>>>(
        hsb, WqkvT, P0, 2048, 5120, 1024, 2048, 1024, 10485760LL, 2048, nullptr, nullptr);
    pack_kernel<<<dim3(1024, 5), 256, 0, stream>>>(P0, P1, cosp, sinp, qnw, knw, Qh, Kh, Vt);
    attn_kernel<<<dim3(512), 256, 0, stream>>>(Qh, Kh, Vt, Oa);
    // O-projection: split-K=3 (1408+1408+1280), fused deterministic reduction
    hipMemsetAsync((void*)cnt, 0, 256 * sizeof(int), stream);
    gemm_bt_kernel<__hip_bfloat16, true><<<dim3(16, 16, 3), 256, 0, stream>>>(
        Oa, WoT, Qb, 2048, 2048, 1408, 4096, 1408, 4194304LL, 4096, out, cnt);
}

// Round 17
// 207.937 us; speedup vs baseline: 1.7466x; 1.7466x over previous
//
#include <hip/hip_runtime.h>
#include <hip/hip_bf16.h>

using short4v = __attribute__((ext_vector_type(4))) short;
using short8 = __attribute__((ext_vector_type(8))) short;
using f32x4  = __attribute__((ext_vector_type(4))) float;

#define SEQ 2048
#define NHEAD 32
#define NKVH 4
#define HDIM 128
// 1/sqrt(128) * log2(e)  -- exp2-domain softmax, folded into Q at pack time
#define QK_SCALE_LOG2 (0.08838834764831845f * 1.44269504088896340f)

__device__ __forceinline__ float fast_exp2(float x) { return __builtin_amdgcn_exp2f(x); }
__device__ __forceinline__ float b2f(short u) {
    return __uint_as_float(((unsigned)(unsigned short)u) << 16);
}
__device__ __forceinline__ short f2bb(float f) {
    __hip_bfloat16 h = __float2bfloat16(f);
    return *reinterpret_cast<short*>(&h);
}
__device__ __forceinline__ void gload_lds16(const __hip_bfloat16* src, __hip_bfloat16* dst) {
    __builtin_amdgcn_global_load_lds((const __attribute__((address_space(1))) void*)src,
                                     (__attribute__((address_space(3))) void*)dst, 16, 0, 0);
}

// ---------------------------------------------------------------- fused prep: cast hs + transpose wq/wk/wv/wo
__global__ __launch_bounds__(256) void prep_kernel(
    const float* __restrict__ hs, __hip_bfloat16* __restrict__ hsb,
    const float* __restrict__ wq, const float* __restrict__ wk, const float* __restrict__ wv,
    const float* __restrict__ wo,
    __hip_bfloat16* __restrict__ WqkvT, __hip_bfloat16* __restrict__ WoT) {
    const int b = blockIdx.x, tid = threadIdx.x;
    if (b < 4096) {
        int i = b * 256 + tid;
        float4 v = ((const float4*)hs)[i];
        __hip_bfloat16 h4[4] = {__float2bfloat16(v.x), __float2bfloat16(v.y),
                                __float2bfloat16(v.z), __float2bfloat16(v.w)};
        ((ushort4*)hsb)[i] = *(ushort4*)h4;
        return;
    }
    __shared__ float tile[32][33];
    const float* W; __hip_bfloat16* Wt; int N, ld, nb, kb;
    if (b < 12288)      { int bb = b - 4096;  W = wq; Wt = WqkvT;                       N = 4096; ld = 2048; nb = (bb & 127) * 32; kb = (bb >> 7) * 32; }
    else if (b < 13312) { int bb = b - 12288; W = wk; Wt = WqkvT + (size_t)4096 * 2048; N = 512;  ld = 2048; nb = (bb & 15) * 32;  kb = (bb >> 4) * 32; }
    else if (b < 14336) { int bb = b - 13312; W = wv; Wt = WqkvT + (size_t)4608 * 2048; N = 512;  ld = 2048; nb = (bb & 15) * 32;  kb = (bb >> 4) * 32; }
    else                { int bb = b - 14336; W = wo; Wt = WoT;                         N = 2048; ld = 4096; nb = (bb & 63) * 32;  kb = (bb >> 6) * 32; }
    int tx = tid & 31, ty = tid >> 5;   // 32 x 8
    for (int j = 0; j < 32; j += 8)
        tile[ty + j][tx] = W[(size_t)(kb + ty + j) * N + nb + tx];
    __syncthreads();
    for (int j = 0; j < 32; j += 8)
        Wt[(size_t)(nb + ty + j) * ld + kb + tx] = __float2bfloat16(tile[tx][ty + j]);
}

// ---------------------------------------------------------------- 3-way bf16 partial add -> fp32 out
__global__ void add3b_kernel(const __hip_bfloat16* __restrict__ a, const __hip_bfloat16* __restrict__ b,
                             const __hip_bfloat16* __restrict__ c, float* __restrict__ o, int n4) {
    int i = blockIdx.x * blockDim.x + threadIdx.x;
    if (i >= n4) return;
    short4v x = ((const short4v*)a)[i];
    short4v y = ((const short4v*)b)[i];
    short4v z = ((const short4v*)c)[i];
    float4 r = {b2f(x[0]) + b2f(y[0]) + b2f(z[0]), b2f(x[1]) + b2f(y[1]) + b2f(z[1]),
                b2f(x[2]) + b2f(y[2]) + b2f(z[2]), b2f(x[3]) + b2f(y[3]) + b2f(z[3])};
    ((float4*)o)[i] = r;
}

// ---------------------------------------------------------------- GEMM: A(M,*)bf16 x Bt(N,*)bf16 -> C(M,N)
// BK=64, XOR-swizzled LDS (R12 structure).
#define BM 128
#define BN 128
#define BK2 64
template <typename OutT>
__global__ __launch_bounds__(256) void gemm_bt_kernel(
    const __hip_bfloat16* __restrict__ A, const __hip_bfloat16* __restrict__ Bt,
    OutT* __restrict__ C, int M, int N, int KextMax, int ld, int koff, long long czstride, int Ktot) {
    const int kstart = blockIdx.z * koff;
    const int Kext = min(KextMax, Ktot - kstart);
    A  += (size_t)kstart;
    Bt += (size_t)kstart;
    C  += (size_t)blockIdx.z * czstride;
    __shared__ __align__(16) __hip_bfloat16 sA[BM * BK2];   // 16 KB
    __shared__ __align__(16) __hip_bfloat16 sB[BN * BK2];   // 16 KB
    const int tid = threadIdx.x;
    const int w = tid >> 6, l = tid & 63;
    const int wr = w >> 1, wc = w & 1;
    const int row0 = blockIdx.y * BM;
    const int col0 = blockIdx.x * BN;
    const int fr = l & 15;
    const int fq = l >> 4;
    const int xs = (fr & 7) << 4;       // read-side XOR (bytes)

    f32x4 acc[4][4] = {};

    for (int k0 = 0; k0 < Kext; k0 += BK2) {
        for (int i = 0; i < 4; ++i) {
            int ch = i * 256 + tid;                 // 0..1023
            int row = ch >> 3;                      // 0..127
            int cb = ((ch & 7) * 16) ^ ((row & 7) << 4);   // pre-swizzled source col (bytes)
            gload_lds16(A  + (size_t)(row0 + row) * ld + k0 + (cb >> 1), &sA[ch * 8]);
            gload_lds16(Bt + (size_t)(col0 + row) * ld + k0 + (cb >> 1), &sB[ch * 8]);
        }
        __syncthreads();
        short8 af[4][2], bfr[4][2];
        for (int m = 0; m < 4; ++m) {
            const char* base = (const char*)sA + (wr * 64 + m * 16 + fr) * 128;
            af[m][0] = *(const short8*)(base + (((fq) * 16)     ^ xs));
            af[m][1] = *(const short8*)(base + (((fq + 4) * 16) ^ xs));
        }
        for (int n = 0; n < 4; ++n) {
            const char* base = (const char*)sB + (wc * 64 + n * 16 + fr) * 128;
            bfr[n][0] = *(const short8*)(base + (((fq) * 16)     ^ xs));
            bfr[n][1] = *(const short8*)(base + (((fq + 4) * 16) ^ xs));
        }
        for (int kk = 0; kk < 2; ++kk)
            for (int m = 0; m < 4; ++m)
                for (int n = 0; n < 4; ++n)
                    acc[m][n] = __builtin_amdgcn_mfma_f32_16x16x32_bf16(af[m][kk], bfr[n][kk], acc[m][n], 0, 0, 0);
        __syncthreads();
    }
    for (int m = 0; m < 4; ++m)
        for (int n = 0; n < 4; ++n)
            for (int r = 0; r < 4; ++r) {
                int row = row0 + wr * 64 + m * 16 + fq * 4 + r;
                int col = col0 + wc * 64 + n * 16 + fr;
                float v = acc[m][n][r];
                if constexpr (__is_same(OutT, float)) C[(size_t)row * N + col] = v;
                else C[(size_t)row * N + col] = __float2bfloat16(v);
            }
}

// ---------------------------------------------------------------- fused partial-add + RMSNorm + RoPE + pack (vectorized)
__global__ __launch_bounds__(256) void pack_kernel(
    const __hip_bfloat16* __restrict__ P0, const __hip_bfloat16* __restrict__ P1,
    const float* __restrict__ cosp, const float* __restrict__ sinp,
    const float* __restrict__ qnw, const float* __restrict__ knw,
    __hip_bfloat16* __restrict__ Qh, __hip_bfloat16* __restrict__ Kh, __hip_bfloat16* __restrict__ Vt) {
    const int tid = threadIdx.x;
    const int rloc = tid >> 4, l16 = tid & 15;
    const int r = blockIdx.y * 16 + rloc;          // 0..79
    const int s = blockIdx.x * 2 + (r >= 40 ? 1 : 0);
    const int slot = (r >= 40) ? r - 40 : r;
    int off;
    if (slot < 32)      off = slot * 128;
    else if (slot < 36) off = 4096 + (slot - 32) * 128;
    else                off = 4608 + (slot - 36) * 128;
    const int d0 = l16 * 4;
    const size_t base = (size_t)s * 5120 + off;

    short4v a0 = *(const short4v*)&P0[base + d0];
    short4v a1 = *(const short4v*)&P0[base + d0 + 64];
    short4v b0 = *(const short4v*)&P1[base + d0];
    short4v b1 = *(const short4v*)&P1[base + d0 + 64];
    float x1[4], x2[4];
    for (int j = 0; j < 4; ++j) {
        x1[j] = b2f(a0[j]) + b2f(b0[j]);
        x2[j] = b2f(a1[j]) + b2f(b1[j]);
    }

    if (slot >= 36) {   // V: cast + transpose to (D,S)
        int t = slot - 36;
        for (int j = 0; j < 4; ++j) {
            Vt[((size_t)t * 128 + d0 + j) * SEQ + s]      = __float2bfloat16(x1[j]);
            Vt[((size_t)t * 128 + d0 + 64 + j) * SEQ + s] = __float2bfloat16(x2[j]);
        }
        return;
    }
    float ss = 0.f;
    for (int j = 0; j < 4; ++j) ss += x1[j] * x1[j] + x2[j] * x2[j];
    for (int x = 1; x < 16; x <<= 1) ss += __shfl_xor(ss, x);
    float rs = rsqrtf(ss * (1.0f / 128.0f) + 1e-6f);

    f32x4 c4 = *(const f32x4*)&cosp[(size_t)s * 128 + d0];   // cos[d]==cos[d+64]
    f32x4 s4 = *(const f32x4*)&sinp[(size_t)s * 128 + d0];
    const float* wgt = (slot < 32) ? qnw : knw;
    f32x4 w1 = *(const f32x4*)&wgt[d0];
    f32x4 w2 = *(const f32x4*)&wgt[d0 + 64];
    const float scl = (slot < 32) ? QK_SCALE_LOG2 : 1.0f;

    short4v o1, o2;
    for (int j = 0; j < 4; ++j) {
        float a = x1[j] * rs * w1[j], b = x2[j] * rs * w2[j];
        o1[j] = f2bb((a * c4[j] - b * s4[j]) * scl);
        o2[j] = f2bb((b * c4[j] + a * s4[j]) * scl);
    }
    __hip_bfloat16* dst;
    if (slot < 32) dst = Qh + ((size_t)slot * SEQ + s) * 128;
    else           dst = Kh + ((size_t)(slot - 32) * SEQ + s) * 128;
    *(short4v*)&dst[d0]      = o1;
    *(short4v*)&dst[d0 + 64] = o2;
}

// ---------------------------------------------------------------- causal GQA flash attention
// Swapped QK^T (R10/R12) + complementary q-tile pairing (R14): each wave
// handles q-tiles qtA = bx>>3 and 127-qtA in one k-loop; 512 uniform blocks.
__global__ __launch_bounds__(256, 2) void attn_kernel(
    const __hip_bfloat16* __restrict__ Qh,  // [NH][S][D], scale*log2e folded
    const __hip_bfloat16* __restrict__ Kh,  // [NKV][S][D]
    const __hip_bfloat16* __restrict__ Vt,  // [NKV][D][S]
    __hip_bfloat16* __restrict__ Oa) {      // [S][NH*D]
    __shared__ __align__(16) __hip_bfloat16 sK[2][64 * 128];   // 2 x 16 KB
    __shared__ __align__(16) __hip_bfloat16 sV[2][128 * 64];   // 2 x 16 KB
    __shared__ __align__(16) __hip_bfloat16 sP[4][16 * 72];    // per-wave P (reused A,B)

    const int tid = threadIdx.x;
    const int w = tid >> 6, l = tid & 63;
    const int bx = blockIdx.x;
    const int y = bx & 7;                      // kv-slice
    const int qtA = bx >> 3;                   // 0..63
    const int qbaseA = qtA * 16;
    const int qbaseB = (127 - qtA) * 16;
    const int hkv = y >> 1;
    const int h = y * 4 + w;                   // this wave's q-head
    const int fr = l & 15, g = l >> 4;

    const __hip_bfloat16* Kp = Kh + (size_t)hkv * SEQ * HDIM;
    const __hip_bfloat16* Vp = Vt + (size_t)hkv * HDIM * SEQ;
    char* myP = (char*)&sP[w][0];

    short8 qfA[4], qfB[4];
    {
        const __hip_bfloat16* QpA = Qh + ((size_t)h * SEQ + qbaseA) * HDIM;
        const __hip_bfloat16* QpB = Qh + ((size_t)h * SEQ + qbaseB) * HDIM;
        for (int c = 0; c < 4; ++c) {
            qfA[c] = *(const short8*)&QpA[fr * HDIM + c * 32 + g * 8];
            qfB[c] = *(const short8*)&QpB[fr * HDIM + c * 32 + g * 8];
        }
    }

    f32x4 oaccA[8] = {}, oaccB[8] = {};
    float msA = -3.0e38f, lsA = 0.f;
    float msB = -3.0e38f, lsB = 0.f;

    const int xr = (fr & 7) << 4;              // XOR-swizzle byte offset (read side)
    const int qgA = qbaseA + fr;
    const int qgB = qbaseB + fr;
    const int nA = ((qbaseA + 15) >> 6) + 1;
    const int nB = ((qbaseB + 15) >> 6) + 1;   // nB >= nA

    auto stage = [&](int buf, int kbase) {
        for (int i = 0; i < 4; ++i) {
            int blk = i * 4 + w;               // 0..15, uniform per wave
            {   // K
                int row = blk * 4 + (l >> 4);
                int cb = ((l & 15) * 16) ^ ((row & 7) << 4);
                gload_lds16(Kp + (size_t)(kbase + row) * HDIM + (cb >> 1), &sK[buf][blk * 512]);
            }
            {   // V
                int row = blk * 8 + (l >> 3);
                int cb = ((l & 7) * 16) ^ ((row & 7) << 4);
                gload_lds16(Vp + (size_t)row * SEQ + kbase + (cb >> 1), &sV[buf][blk * 512]);
            }
        }
    };

    // one q-tile's per-k-tile work (swapped QK^T softmax); all indices static
#define PROCESS(QF, OACC, MS, LS, QG, QBASE)                                           \
    {                                                                                  \
        f32x4 s[4] = {};                                                               \
        __builtin_amdgcn_s_setprio(1);                                                 \
        for (int j = 0; j < 4; ++j) {                                                  \
            const __hip_bfloat16* kp = &sK[buf][(j * 16 + fr) * 128];                  \
            for (int c = 0; c < 4; ++c) {                                              \
                short8 kf = *(const short8*)&kp[((c * 64 + g * 16) ^ xr) >> 1];        \
                s[j] = __builtin_amdgcn_mfma_f32_16x16x32_bf16(kf, QF[c], s[j], 0, 0, 0); \
            }                                                                          \
        }                                                                              \
        __builtin_amdgcn_s_setprio(0);                                                 \
        float v[4][4];                                                                 \
        const bool full = (kbase + 63 <= (QBASE));                                     \
        if (full) {                                                                    \
            for (int j = 0; j < 4; ++j)                                                \
                for (int r = 0; r < 4; ++r) v[j][r] = s[j][r];                         \
        } else {                                                                       \
            const int kb0 = kbase + g * 4;                                             \
            for (int j = 0; j < 4; ++j)                                                \
                for (int r = 0; r < 4; ++r)                                            \
                    v[j][r] = (kb0 + j * 16 + r <= (QG)) ? s[j][r] : -1e30f;           \
        }                                                                              \
        float m0 = fmaxf(fmaxf(v[0][0], v[0][1]), fmaxf(v[0][2], v[0][3]));            \
        float m1 = fmaxf(fmaxf(v[1][0], v[1][1]), fmaxf(v[1][2], v[1][3]));            \
        float m2 = fmaxf(fmaxf(v[2][0], v[2][1]), fmaxf(v[2][2], v[2][3]));            \
        float m3 = fmaxf(fmaxf(v[3][0], v[3][1]), fmaxf(v[3][2], v[3][3]));            \
        float m = fmaxf(fmaxf(m0, m1), fmaxf(m2, m3));                                 \
        m = fmaxf(m, __shfl_xor(m, 16));                                               \
        m = fmaxf(m, __shfl_xor(m, 32));                                               \
        if (__any(m > MS + 12.0f)) {                                                   \
            float mnew = fmaxf(MS, m);                                                 \
            float corr = fast_exp2(MS - mnew);                                         \
            MS = mnew;                                                                 \
            LS *= corr;                                                                \
            float c0 = __shfl(corr, g * 4 + 0);                                        \
            float c1 = __shfl(corr, g * 4 + 1);                                        \
            float c2 = __shfl(corr, g * 4 + 2);                                        \
            float c3 = __shfl(corr, g * 4 + 3);                                        \
            for (int dt = 0; dt < 8; ++dt) {                                           \
                OACC[dt][0] *= c0; OACC[dt][1] *= c1;                                  \
                OACC[dt][2] *= c2; OACC[dt][3] *= c3;                                  \
            }                                                                          \
        }                                                                              \
        for (int j = 0; j < 4; ++j) {                                                  \
            float e0 = fast_exp2(v[j][0] - MS);                                        \
            float e1 = fast_exp2(v[j][1] - MS);                                        \
            float e2 = fast_exp2(v[j][2] - MS);                                        \
            float e3 = fast_exp2(v[j][3] - MS);                                        \
            LS += (e0 + e1) + (e2 + e3);                                               \
            short4v pw = {f2bb(e0), f2bb(e1), f2bb(e2), f2bb(e3)};                     \
            *(short4v*)(myP + fr * 144 + j * 32 + g * 8) = pw;                         \
        }                                                                              \
        short8 pa0 = *(const short8*)(myP + fr * 144 + g * 16);                        \
        short8 pa1 = *(const short8*)(myP + fr * 144 + 64 + g * 16);                   \
        __builtin_amdgcn_s_setprio(1);                                                 \
        for (int dt = 0; dt < 8; ++dt) {                                               \
            const __hip_bfloat16* vp = &sV[buf][(dt * 16 + fr) * 64];                  \
            short8 vb0 = *(const short8*)&vp[((g * 16)      ^ xr) >> 1];               \
            short8 vb1 = *(const short8*)&vp[((g * 16 + 64) ^ xr) >> 1];               \
            OACC[dt] = __builtin_amdgcn_mfma_f32_16x16x32_bf16(pa0, vb0, OACC[dt], 0, 0, 0); \
            OACC[dt] = __builtin_amdgcn_mfma_f32_16x16x32_bf16(pa1, vb1, OACC[dt], 0, 0, 0); \
        }                                                                              \
        __builtin_amdgcn_s_setprio(0);                                                 \
    }

    stage(0, 0);
    __syncthreads();                            // drains vmcnt(0): tile 0 ready

    for (int t = 0; t < nB; ++t) {
        const int kbase = t * 64;
        const int buf = t & 1;
        if (t + 1 < nB) stage(buf ^ 1, kbase + 64);   // overlap with compute

        if (t < nA) PROCESS(qfA, oaccA, msA, lsA, qgA, qbaseA);
        PROCESS(qfB, oaccB, msB, lsB, qgB, qbaseB);

        __syncthreads();   // next tile staged (vmcnt 0) + all waves done with buf[t]
    }
#undef PROCESS

    // ---- finalize both q-tiles
    lsA += __shfl_xor(lsA, 16); lsA += __shfl_xor(lsA, 32);
    lsB += __shfl_xor(lsB, 16); lsB += __shfl_xor(lsB, 32);
    float invA[4], invB[4];
    for (int r = 0; r < 4; ++r) {
        invA[r] = 1.0f / __shfl(lsA, g * 4 + r);
        invB[r] = 1.0f / __shfl(lsB, g * 4 + r);
    }
    for (int dt = 0; dt < 8; ++dt)
        for (int r = 0; r < 4; ++r) {
            int qA = qbaseA + g * 4 + r;
            int qB = qbaseB + g * 4 + r;
            Oa[(size_t)qA * (NHEAD * HDIM) + h * HDIM + dt * 16 + fr] =
                __float2bfloat16(oaccA[dt][r] * invA[r]);
            Oa[(size_t)qB * (NHEAD * HDIM) + h * HDIM + dt * 16 + fr] =
                __float2bfloat16(oaccB[dt][r] * invB[r]);
        }
}

// ---------------------------------------------------------------- launch
extern "C" void kernel_launch(void* const* d_in, const int* in_sizes, int n_in,
                              void* d_out, int out_size, void* d_ws, size_t ws_size,
                              hipStream_t stream) {
    const float* hs   = (const float*)d_in[0];
    const float* cosp = (const float*)d_in[1];
    const float* sinp = (const float*)d_in[2];
    const float* wq   = (const float*)d_in[3];
    const float* wk   = (const float*)d_in[4];
    const float* wv   = (const float*)d_in[5];
    const float* wo   = (const float*)d_in[6];
    const float* qnw  = (const float*)d_in[7];
    const float* knw  = (const float*)d_in[8];
    float* out = (float*)d_out;
    char* ws = (char*)d_ws;

    // workspace timeline (88,080,384 B):
    // phase1 prep:  hsb[0,8.39M) WqkvT[8.39M,29.36M) WoT[29.36M,46.14M)
    // phase2 gemm1: P0[46.14M,67.11M) P1[67.11M,88.08M)  (bf16, split-K=2)
    // phase3 pack:  Qh[8.39M,25.17M) Kh[25.17M,27.26M) Vt[27.26M,29.36M)  (over dead WqkvT)
    // phase4 attn:  Oa[46.14M,62.91M)                                     (over dead P0)
    // phase5 gemm2: Qb[0,25.17M) split-K=3 partials                       (over dead hsb/Qh/Kh/Vt)
    __hip_bfloat16* hsb    = (__hip_bfloat16*)(ws);
    __hip_bfloat16* WqkvT  = (__hip_bfloat16*)(ws + 8388608);
    __hip_bfloat16* WoT    = (__hip_bfloat16*)(ws + 29360128);
    __hip_bfloat16* P0     = (__hip_bfloat16*)(ws + 46137344);
    __hip_bfloat16* P1     = (__hip_bfloat16*)(ws + 67108864);
    __hip_bfloat16* Qh     = (__hip_bfloat16*)(ws + 8388608);
    __hip_bfloat16* Kh     = (__hip_bfloat16*)(ws + 25165824);
    __hip_bfloat16* Vt     = (__hip_bfloat16*)(ws + 27262976);
    __hip_bfloat16* Oa     = (__hip_bfloat16*)(ws + 46137344);
    __hip_bfloat16* Qb     = (__hip_bfloat16*)(ws);              // 3 x 8,388,608 B

    prep_kernel<<<22528, 256, 0, stream>>>(hs, hsb, wq, wk, wv, wo, WqkvT, WoT);
    // QKV projection, split-K=2 (K=1024 each, 16 BK64-steps), bf16 partials
    gemm_bt_kernel<__hip_bfloat16><<<dim3(40, 16, 2), 256, 0, stream>>>(
        hsb, WqkvT, P0, 2048, 5120, 1024, 2048, 1024, 10485760LL, 2048);
    pack_kernel<<<dim3(1024, 5), 256, 0, stream>>>(P0, P1, cosp, sinp, qnw, knw, Qh, Kh, Vt);
    attn_kernel<<<dim3(512), 256, 0, stream>>>(Qh, Kh, Vt, Oa);
    // O-projection: split-K=3 (1408+1408+1280, all /64), bf16 partials
    gemm_bt_kernel<__hip_bfloat16><<<dim3(16, 16, 3), 256, 0, stream>>>(
        Oa, WoT, Qb, 2048, 2048, 1408, 4096, 1408, 4194304LL, 4096);
    add3b_kernel<<<4096, 256, 0, stream>>>(Qb, Qb + 4194304, Qb + 8388608, out, (2048 * 2048) / 4);
}